// Round 2
// baseline (205.567 us; speedup 1.0000x reference)
//
#include <hip/hip_runtime.h>

// NeuromodulatedAttention — MI355X (gfx950), round 9
//
// ALGEBRA: (1) dopamine/serotonin "mod" is a per-row constant added before the
// per-row mean/std normalization -> cancels exactly (both MLPs are dead code).
// (2) the mean subtraction is a per-row constant inside softmax -> also cancels.
// Effective:  out = softmax( S * istd_row ) @ V,
//   S = Q K^T / sqrt(512),  istd_row = 1/(std(S_row, ddof=1) + 1e-6).
//
// Round-9 delta vs round 8 (total 175.8us, flat vs r7 -> qk/pv micro-tuning was
// not the bottleneck): ELIMINATE THE P TENSOR.
//   * softmax_kernel -> stats_kernel: read S once, write only a1=log2e/(std+eps)
//     per row (32 KB). No exp pass, no P write (saves 33.5 MB write + dispatch
//     shrink ~15-20us -> ~7us).
//   * pv_gemm -> fused exp+PV: A-path is reg-staged S(f16) -> exp2 -> bf16 ->
//     swizzled ds_write (same LDS image as the old gload of P, MFMA loop
//     unchanged). den accumulated from the same bf16-rounded p values in-block;
//     global den buffer gone. S loads for iter+1 prefetched during MFMA phase.
//   * qk / prep / fallback: byte-identical to round 8 (attribution).

#define BB 4
#define SS 2048
#define DD 512
#define SCALE 0.044194173824159216f  // 1/sqrt(512)
#define LOG2E 1.4426950408889634f

typedef __bf16 bf16;
typedef _Float16 f16;
typedef bf16 bf16x2 __attribute__((ext_vector_type(2)));
typedef bf16 bf16x4 __attribute__((ext_vector_type(4)));
typedef bf16 bf16x8 __attribute__((ext_vector_type(8)));
typedef f16  f16x8  __attribute__((ext_vector_type(8)));
typedef float f32x16 __attribute__((ext_vector_type(16)));

// async 16B/lane global->LDS; LDS dest = wave-uniform base + lane*16.
__device__ __forceinline__ void gload_lds16(const bf16* g, bf16* l) {
  __builtin_amdgcn_global_load_lds(
      (const __attribute__((address_space(1))) void*)g,
      (__attribute__((address_space(3))) void*)l, 16, 0, 0);
}

// ---------------- K1: prep = cast Q,K (bf16) + transpose V (bf16 [b][d][s]) ----

__global__ void prep_kernel(const float* __restrict__ Q, const float* __restrict__ K,
                            const float* __restrict__ V,
                            bf16* __restrict__ Qb, bf16* __restrict__ Kb,
                            bf16* __restrict__ Vt) {
  __shared__ bf16 tile[64][80];
  const int bx = blockIdx.x;
  const int t = threadIdx.x;
  if (bx < 2048) {
    // cast 8 elems of Q and K per thread
    size_t i = ((size_t)bx * 256 + t) * 8;
    float4 a0 = *(const float4*)(Q + i);
    float4 a1 = *(const float4*)(Q + i + 4);
    bf16x8 qa = { (bf16)a0.x, (bf16)a0.y, (bf16)a0.z, (bf16)a0.w,
                  (bf16)a1.x, (bf16)a1.y, (bf16)a1.z, (bf16)a1.w };
    *(bf16x8*)(Qb + i) = qa;
    float4 b0 = *(const float4*)(K + i);
    float4 b1 = *(const float4*)(K + i + 4);
    bf16x8 ka = { (bf16)b0.x, (bf16)b0.y, (bf16)b0.z, (bf16)b0.w,
                  (bf16)b1.x, (bf16)b1.y, (bf16)b1.z, (bf16)b1.w };
    *(bf16x8*)(Kb + i) = ka;
  } else {
    // V transpose, 64x64 tile
    const int tt = bx - 2048;
    const int s0 = (tt & 31) * 64, d0 = ((tt >> 5) & 7) * 64, b = tt >> 8;
    const int r16 = t >> 4;
    const int c4  = (t & 15) * 4;
#pragma unroll
    for (int i = 0; i < 4; ++i) {
      int r = i * 16 + r16;
      float4 v = *(const float4*)&V[((size_t)b * SS + s0 + r) * DD + d0 + c4];
      tile[c4 + 0][r] = (bf16)v.x;
      tile[c4 + 1][r] = (bf16)v.y;
      tile[c4 + 2][r] = (bf16)v.z;
      tile[c4 + 3][r] = (bf16)v.w;
    }
    __syncthreads();
    const int dr8 = t >> 3;
    const int sc8 = (t & 7) * 8;
#pragma unroll
    for (int i = 0; i < 2; ++i) {
      int dr = i * 32 + dr8;
      bf16x8 o = *(const bf16x8*)&tile[dr][sc8];
      *(bf16x8*)&Vt[((size_t)b * DD + d0 + dr) * SS + s0 + sc8] = o;
    }
  }
}

// ---------------- K2: QK^T GEMM -> S f16 (unchanged from round 8) ----------------
// grid (16 qt, 8 kt-pair, 4 b), 256 thr (4 waves). Each block: 128q x 256k
// (two 128x128 k-tiles sharing one staged A tile). BK=64 (8 iters).
// Wave (wq=w&1, wn=w>>1) owns the 64x64 quadrant of each 128x128 sub-tile.
// LDS rows 128B, chunk slot s of row r holds global chunk s^(r&7).

__launch_bounds__(256, 2)
__global__ void qk_gemm_kernel(const bf16* __restrict__ Qb, const bf16* __restrict__ Kb,
                               f16* __restrict__ Sp) {
  __shared__ bf16 At[128 * 64];
  __shared__ bf16 Bt[2][128 * 64];

  const int tid  = threadIdx.x;
  const int w    = tid >> 6;
  const int lane = tid & 63;
  const int l31  = lane & 31;
  const int lh   = lane >> 5;
  const int qt = blockIdx.x, kt2 = blockIdx.y, b = blockIdx.z;
  const int q0 = qt * 128, k0 = kt2 * 256;
  const int wq = w & 1, wn = w >> 1;
  const int m0 = wq * 64, n0 = wn * 64;

  const int srow = lane >> 3;          // row within 8-row staging group
  const int sg   = (lane & 7) ^ srow;  // swizzled global chunk index
  const bf16* gA = Qb + ((size_t)b * SS + q0) * DD;
  const bf16* gB = Kb + ((size_t)b * SS + k0) * DD;

  f32x16 acc[2][4];                    // [k-tile half][2*rowhalf + colhalf]
#pragma unroll
  for (int h = 0; h < 2; ++h)
#pragma unroll
    for (int u = 0; u < 4; ++u) acc[h][u] = (f32x16){};

  for (int dc = 0; dc < DD; dc += 64) {
    __syncthreads();
#pragma unroll
    for (int j = 0; j < 4; ++j) {
      int row = w * 32 + j * 8 + srow;
      gload_lds16(gA + (size_t)row * DD + dc + sg * 8, At + (w * 32 + j * 8) * 64);
      gload_lds16(gB + (size_t)row * DD + dc + sg * 8, Bt[0] + (w * 32 + j * 8) * 64);
      gload_lds16(gB + (size_t)(128 + row) * DD + dc + sg * 8,
                  Bt[1] + (w * 32 + j * 8) * 64);
    }
    __syncthreads();
#pragma unroll
    for (int kk = 0; kk < 4; ++kk) {
      int c = kk * 2 + lh;
      int ra0 = m0 + l31, ra1 = m0 + 32 + l31;
      int rb0 = n0 + l31, rb1 = n0 + 32 + l31;
      bf16x8 a0 = *(const bf16x8*)&At[ra0 * 64 + ((c ^ (ra0 & 7)) << 3)];
      bf16x8 a1 = *(const bf16x8*)&At[ra1 * 64 + ((c ^ (ra1 & 7)) << 3)];
#pragma unroll
      for (int h = 0; h < 2; ++h) {
        bf16x8 b0 = *(const bf16x8*)&Bt[h][rb0 * 64 + ((c ^ (rb0 & 7)) << 3)];
        bf16x8 b1 = *(const bf16x8*)&Bt[h][rb1 * 64 + ((c ^ (rb1 & 7)) << 3)];
        acc[h][0] = __builtin_amdgcn_mfma_f32_32x32x16_bf16(a0, b0, acc[h][0], 0, 0, 0);
        acc[h][1] = __builtin_amdgcn_mfma_f32_32x32x16_bf16(a0, b1, acc[h][1], 0, 0, 0);
        acc[h][2] = __builtin_amdgcn_mfma_f32_32x32x16_bf16(a1, b0, acc[h][2], 0, 0, 0);
        acc[h][3] = __builtin_amdgcn_mfma_f32_32x32x16_bf16(a1, b1, acc[h][3], 0, 0, 0);
      }
    }
  }

  int qrow[16];
#pragma unroll
  for (int r = 0; r < 16; ++r) qrow[r] = (r & 3) + 8 * (r >> 2) + 4 * lh;

  // epilogue: pure f16 stores (stats are computed by stats_kernel from S)
#pragma unroll
  for (int h = 0; h < 2; ++h) {
    f16* Sb = Sp + ((size_t)b * SS + q0) * SS + k0 + h * 128 + n0;
#pragma unroll
    for (int i = 0; i < 2; ++i) {
      const f32x16& A0 = acc[h][i * 2 + 0];
      const f32x16& A1 = acc[h][i * 2 + 1];
#pragma unroll
      for (int r = 0; r < 16; ++r) {
        f16* Sr = Sb + (size_t)(m0 + i * 32 + qrow[r]) * SS;
        Sr[l31]      = (f16)(A0[r] * SCALE);
        Sr[32 + l31] = (f16)(A1[r] * SCALE);
      }
    }
  }
}

// ---------------- K3: stats (sum/sumsq -> a1 per row), no exp, no P ----------------
// grid (2048, 4), 256 thr; block = one q-row (2048 f16, 8/thread).

__global__ void stats_kernel(const f16* __restrict__ Sp, float* __restrict__ a1out) {
  __shared__ float redS[4], redQ[4];
  const int row = blockIdx.x, b = blockIdx.y;
  const int tid = threadIdx.x;
  const int lane = tid & 63, w = tid >> 6;
  const size_t base = ((size_t)b * SS + row) * SS;

  f16x8 hv = *(const f16x8*)&Sp[base + tid * 8];
  float s = 0.f, q = 0.f;
#pragma unroll
  for (int j = 0; j < 8; ++j) {
    float v = (float)hv[j];
    s += v;
    q += v * v;
  }
#pragma unroll
  for (int m = 32; m >= 1; m >>= 1) { s += __shfl_xor(s, m); q += __shfl_xor(q, m); }
  if (lane == 0) { redS[w] = s; redQ[w] = q; }
  __syncthreads();
  if (tid == 0) {
    s = redS[0] + redS[1] + redS[2] + redS[3];
    q = redQ[0] + redQ[1] + redQ[2] + redQ[3];
    float mean = s * (1.0f / 2048.0f);
    float var  = (q - 2048.0f * mean * mean) * (1.0f / 2047.0f);
    var = fmaxf(var, 0.0f);
    // p = exp((s-mean)*istd); per-row exp(-mean*istd) cancels in softmax.
    a1out[b * SS + row] = LOG2E / (sqrtf(var) + 1e-6f);
  }
}

// ---------------- K4: fused exp + PV GEMM -> out (fp32) ----------------
// grid (16 qt, 8 dt, 4 b), 256 thr (4 waves). Tile 128q x 64d, BK=128 (16 iters).
// A-path: reg-staged S(f16) -> exp2(v*a1) -> bf16 -> swizzled ds_write, producing
// the SAME LDS image (chunk slot s of row r holds global chunk s^(r&7)) as the
// old gload of P -> MFMA loop identical to round 8 (wave (wq,wk): 64q x 64d,
// split-K halves of each 128-chunk, merged through LDS at the end).
// den accumulated per-thread from the bf16-rounded p (exactly the old softmax
// denominator), reduced in-block; out scaled by 1/den locally.
// Exp thread map: row er=tid>>1, chunks c=(tid&1)+2j (stride-2 => ds_write
// banks 2-way = free). S loads for iter+1 prefetched during the MFMA phase.

__launch_bounds__(256, 2)
__global__ void pv_fused_kernel(const f16* __restrict__ Sp, const bf16* __restrict__ Vt,
                                const float* __restrict__ a1p, float* __restrict__ out) {
  __shared__ bf16 At[128 * 128];   // 32 KB (reused as f32[128][64] scratch at end)
  __shared__ bf16 Bt[64 * 128];    // 16 KB
  __shared__ float denp[256];
  __shared__ float dinv[128];

  const int tid  = threadIdx.x;
  const int w    = tid >> 6;
  const int lane = tid & 63;
  const int l31  = lane & 31;
  const int lh   = lane >> 5;
  const int qt = blockIdx.x, dt = blockIdx.y, b = blockIdx.z;
  const int q0 = qt * 128, d0 = dt * 64;
  const int wq = w & 1, wk = w >> 1;

  // exp staging: this thread owns row er, chunks (e0 + 2j), j=0..7
  const int er = tid >> 1;
  const int e0 = tid & 1;
  const float a1 = a1p[b * SS + q0 + er];
  const f16* gS = Sp + ((size_t)b * SS + q0 + er) * SS;
  bf16* lA = At + er * 128;

  const int srow4 = lane >> 4;     // 0..3 row within 4-row staging group
  const int sg16  = lane & 15;     // slot index (16 chunks/row)
  const bf16* gB = Vt + ((size_t)b * DD + d0) * SS;

  f32x16 acc[2][2];
#pragma unroll
  for (int i = 0; i < 2; ++i)
#pragma unroll
    for (int j = 0; j < 2; ++j) acc[i][j] = (f32x16){};

  f16x8 hv[8];
#pragma unroll
  for (int j = 0; j < 8; ++j)
    hv[j] = *(const f16x8*)&gS[(e0 + 2 * j) * 8];

  float loc = 0.f;   // this thread's share of den[er]

  for (int kc = 0; kc < SS; kc += 128) {
    __syncthreads();               // prev compute done -> LDS writable
    // B stage: direct async global->LDS (linear dest, pre-swizzled source)
#pragma unroll
    for (int j = 0; j < 4; ++j) {
      int row = w * 16 + j * 4 + srow4;
      gload_lds16(gB + (size_t)row * SS + kc + ((sg16 ^ (row & 7)) * 8),
                  Bt + (w * 16 + j * 4) * 128);
    }
    // A stage: exp + swizzled ds_write from prefetched regs
#pragma unroll
    for (int j = 0; j < 8; ++j) {
      int c = e0 + 2 * j;
      bf16x8 pb;
#pragma unroll
      for (int u = 0; u < 8; ++u) {
        float p = exp2f((float)hv[j][u] * a1);
        bf16 pc = (bf16)p;
        pb[u] = pc;
        loc += (float)pc;          // denominator from the bf16 values PV uses
      }
      *(bf16x8*)&lA[(c ^ (er & 7)) << 3] = pb;
    }
    __syncthreads();               // drains B gloads + A ds_writes

    // prefetch next S chunk into regs; completes under the MFMA phase
    if (kc + 128 < SS) {
#pragma unroll
      for (int j = 0; j < 8; ++j)
        hv[j] = *(const f16x8*)&gS[kc + 128 + (e0 + 2 * j) * 8];
    }

#pragma unroll
    for (int kk = 0; kk < 4; ++kk) {
      int c = wk * 8 + kk * 2 + lh;          // wave's 64-k half of the 128-chunk
      int ra0 = wq * 64 + l31, ra1 = wq * 64 + 32 + l31;
      int rb0 = l31, rb1 = 32 + l31;
      bf16x8 a0 = *(const bf16x8*)&At[ra0 * 128 + ((c ^ (ra0 & 7)) << 3)];
      bf16x8 a1f = *(const bf16x8*)&At[ra1 * 128 + ((c ^ (ra1 & 7)) << 3)];
      bf16x8 b0 = *(const bf16x8*)&Bt[rb0 * 128 + ((c ^ (rb0 & 7)) << 3)];
      bf16x8 b1 = *(const bf16x8*)&Bt[rb1 * 128 + ((c ^ (rb1 & 7)) << 3)];
      acc[0][0] = __builtin_amdgcn_mfma_f32_32x32x16_bf16(a0, b0, acc[0][0], 0, 0, 0);
      acc[0][1] = __builtin_amdgcn_mfma_f32_32x32x16_bf16(a0, b1, acc[0][1], 0, 0, 0);
      acc[1][0] = __builtin_amdgcn_mfma_f32_32x32x16_bf16(a1f, b0, acc[1][0], 0, 0, 0);
      acc[1][1] = __builtin_amdgcn_mfma_f32_32x32x16_bf16(a1f, b1, acc[1][1], 0, 0, 0);
    }
  }

  __syncthreads();                 // all LDS reads of the final tile done
  denp[tid] = loc;

  int qrow[16];
#pragma unroll
  for (int r = 0; r < 16; ++r) qrow[r] = (r & 3) + 8 * (r >> 2) + 4 * lh;

  float* Lred = (float*)At;        // 128x64 f32 = 32 KB, exactly At
  if (wk == 1) {
#pragma unroll
    for (int i = 0; i < 2; ++i)
#pragma unroll
      for (int j = 0; j < 2; ++j)
#pragma unroll
        for (int r = 0; r < 16; ++r) {
          int row = wq * 64 + i * 32 + qrow[r];
          Lred[row * 64 + j * 32 + l31] = acc[i][j][r];
        }
  }
  __syncthreads();
  if (tid < 128) dinv[tid] = 1.0f / (denp[2 * tid] + denp[2 * tid + 1]);
  __syncthreads();
  if (wk == 0) {
    float* Ob = out + ((size_t)b * SS + q0) * DD + d0;
#pragma unroll
    for (int i = 0; i < 2; ++i)
#pragma unroll
      for (int r = 0; r < 16; ++r) {
        int row = wq * 64 + i * 32 + qrow[r];
        float iv = dinv[row];
        float* Or = Ob + (size_t)row * DD;
        Or[l31]      = (acc[i][0][r] + Lred[row * 64 + l31]) * iv;
        Or[32 + l31] = (acc[i][1][r] + Lred[row * 64 + 32 + l31]) * iv;
      }
  }
}

// ---------------- fallback (round-1 kernel, zero workspace) ----------------

#define QS_STRIDE 520
#define KS_STRIDE 72
#define VT_STRIDE 18
#define PS_STRIDE 136

__device__ __forceinline__ f32x16 qk_tile(const float* __restrict__ Kb,
                                          const bf16* __restrict__ Qsl,
                                          bf16* __restrict__ KVw,
                                          int l31, int lh8, int lane) {
  f32x16 acc = {};
  for (int dc = 0; dc < DD; dc += 64) {
#pragma unroll
    for (int i = 0; i < 8; ++i) {
      int f = i * 64 + lane;
      int row = f >> 4;
      int c4 = (f & 15) * 4;
      float4 v = *(const float4*)(Kb + row * DD + dc + c4);
      bf16x4 h = { (bf16)v.x, (bf16)v.y, (bf16)v.z, (bf16)v.w };
      *(bf16x4*)&KVw[row * KS_STRIDE + c4] = h;
    }
#pragma unroll
    for (int ks = 0; ks < 4; ++ks) {
      bf16x8 a  = *(const bf16x8*)&Qsl[l31 * QS_STRIDE + dc + ks * 16 + lh8];
      bf16x8 bb = *(const bf16x8*)&KVw[l31 * KS_STRIDE + ks * 16 + lh8];
      acc = __builtin_amdgcn_mfma_f32_32x32x16_bf16(a, bb, acc, 0, 0, 0);
    }
  }
  return acc;
}

__launch_bounds__(256, 1)
__global__ void nm_attn_kernel(const float* __restrict__ Qp,
                               const float* __restrict__ Kp,
                               const float* __restrict__ Vp,
                               float* __restrict__ Op) {
  __shared__ bf16 Qs[32 * QS_STRIDE];
  __shared__ bf16 KVu[4][32 * KS_STRIDE];
  __shared__ bf16 Psl[32 * PS_STRIDE];
  __shared__ float redA[4][32];
  __shared__ float redB[4][32];
  __shared__ float a0v[32], a1v[32], idv[32];

  const int tid  = threadIdx.x;
  const int w    = tid >> 6;
  const int lane = tid & 63;
  const int l31  = lane & 31;
  const int lh8  = (lane >> 5) * 8;
  const int b    = blockIdx.y;
  const int q0   = blockIdx.x * 32;

  {
    const float* Qbase = Qp + (size_t)(b * SS + q0) * DD;
#pragma unroll
    for (int i = 0; i < 16; ++i) {
      int f = i * 256 + tid;
      int row = f >> 7;
      int c4 = (f & 127) * 4;
      float4 v = *(const float4*)(Qbase + row * DD + c4);
      bf16x4 h = { (bf16)v.x, (bf16)v.y, (bf16)v.z, (bf16)v.w };
      *(bf16x4*)&Qs[row * QS_STRIDE + c4] = h;
    }
  }
  __syncthreads();

  int qrow[16];
#pragma unroll
  for (int r = 0; r < 16; ++r) qrow[r] = (r & 3) + 8 * (r >> 2) + 4 * (lane >> 5);

  float sumv[16], sqv[16];
#pragma unroll
  for (int r = 0; r < 16; ++r) { sumv[r] = 0.f; sqv[r] = 0.f; }

  for (int kt = 0; kt < 16; ++kt) {
    const float* Kb = Kp + (size_t)(b * SS + kt * 128 + w * 32) * DD;
    f32x16 acc = qk_tile(Kb, Qs, KVu[w], l31, lh8, lane);
#pragma unroll
    for (int r = 0; r < 16; ++r) {
      float s = acc[r] * SCALE;
      sumv[r] += s;
      sqv[r]  += s * s;
    }
  }

#pragma unroll
  for (int r = 0; r < 16; ++r) {
    float v1 = sumv[r], v2 = sqv[r];
#pragma unroll
    for (int m = 16; m >= 1; m >>= 1) {
      v1 += __shfl_xor(v1, m);
      v2 += __shfl_xor(v2, m);
    }
    if (l31 == 0) { redA[w][qrow[r]] = v1; redB[w][qrow[r]] = v2; }
  }
  __syncthreads();
  if (tid < 32) {
    float s  = redA[0][tid] + redA[1][tid] + redA[2][tid] + redA[3][tid];
    float sq = redB[0][tid] + redB[1][tid] + redB[2][tid] + redB[3][tid];
    float mean = s * (1.0f / 2048.0f);
    float var = (sq - 2048.0f * mean * mean) * (1.0f / 2047.0f);
    var = fmaxf(var, 0.0f);
    float istd = 1.0f / (sqrtf(var) + 1e-6f);
    a1v[tid] = istd * LOG2E;
    a0v[tid] = -mean * istd * LOG2E;
  }
  __syncthreads();

  float a0r[16], a1r[16], den[16];
#pragma unroll
  for (int r = 0; r < 16; ++r) {
    a0r[r] = a0v[qrow[r]];
    a1r[r] = a1v[qrow[r]];
    den[r] = 0.f;
  }

  f32x16 Oa[4] = {};

  for (int kt = 0; kt < 16; ++kt) {
    const float* Kb = Kp + (size_t)(b * SS + kt * 128 + w * 32) * DD;
    f32x16 acc = qk_tile(Kb, Qs, KVu[w], l31, lh8, lane);

    __syncthreads();
#pragma unroll
    for (int r = 0; r < 16; ++r) {
      float s = acc[r] * SCALE;
      float p = exp2f(fmaf(s, a1r[r], a0r[r]));
      den[r] += p;
      Psl[qrow[r] * PS_STRIDE + w * 32 + l31] = (bf16)p;
    }
    __syncthreads();

    const float* Vb = Vp + (size_t)(b * SS + kt * 128) * DD + w * 128 + 2 * lane;
    bf16* Vts = KVu[w];
    const int d0 = 2 * lane;
    for (int ks2 = 0; ks2 < 8; ++ks2) {
      const float* Vk = Vb + ks2 * 16 * DD;
#pragma unroll
      for (int i = 0; i < 8; ++i) {
        float2 va = *(const float2*)(Vk + (2 * i) * DD);
        float2 vc = *(const float2*)(Vk + (2 * i + 1) * DD);
        bf16x2 h0 = { (bf16)va.x, (bf16)vc.x };
        bf16x2 h1 = { (bf16)va.y, (bf16)vc.y };
        *(bf16x2*)&Vts[d0 * VT_STRIDE + 2 * i] = h0;
        *(bf16x2*)&Vts[(d0 + 1) * VT_STRIDE + 2 * i] = h1;
      }
      bf16x8 aP = *(const bf16x8*)&Psl[l31 * PS_STRIDE + ks2 * 16 + lh8];
#pragma unroll
      for (int dt = 0; dt < 4; ++dt) {
        const bf16* vr = &Vts[(dt * 32 + l31) * VT_STRIDE + lh8];
        bf16x2 e0 = *(const bf16x2*)(vr + 0);
        bf16x2 e1 = *(const bf16x2*)(vr + 2);
        bf16x2 e2 = *(const bf16x2*)(vr + 4);
        bf16x2 e3 = *(const bf16x2*)(vr + 6);
        bf16x8 bV = { e0.x, e0.y, e1.x, e1.y, e2.x, e2.y, e3.x, e3.y };
        Oa[dt] = __builtin_amdgcn_mfma_f32_32x32x16_bf16(aP, bV, Oa[dt], 0, 0, 0);
      }
    }
  }

#pragma unroll
  for (int r = 0; r < 16; ++r) {
    float v1 = den[r];
#pragma unroll
    for (int m = 16; m >= 1; m >>= 1) v1 += __shfl_xor(v1, m);
    if (l31 == 0) redA[w][qrow[r]] = v1;
  }
  __syncthreads();
  if (tid < 32) {
    float t = redA[0][tid] + redA[1][tid] + redA[2][tid] + redA[3][tid];
    idv[tid] = 1.0f / t;
  }
  __syncthreads();

  float idr[16];
#pragma unroll
  for (int r = 0; r < 16; ++r) idr[r] = idv[qrow[r]];

  float* Ob = Op + (size_t)(b * SS + q0) * DD + w * 128;
#pragma unroll
  for (int dt = 0; dt < 4; ++dt) {
#pragma unroll
    for (int r = 0; r < 16; ++r) {
      Ob[qrow[r] * DD + dt * 32 + l31] = Oa[dt][r] * idr[r];
    }
  }
}

// ---------------- launcher ----------------

extern "C" void kernel_launch(void* const* d_in, const int* in_sizes, int n_in,
                              void* d_out, int out_size, void* d_ws, size_t ws_size,
                              hipStream_t stream) {
  const float* Q = (const float*)d_in[0];
  const float* K = (const float*)d_in[1];
  const float* V = (const float*)d_in[2];
  float* out = (float*)d_out;
  (void)in_sizes; (void)n_in; (void)out_size;

  const size_t E  = (size_t)BB * SS * DD;   // 4,194,304 elems / tensor
  const size_t SE = (size_t)BB * SS * SS;   // 16,777,216 score elems

  // ws layout: [Qb bf16 E][Kb bf16 E][Vt bf16 E][S f16 SE][a1 B*S f32]
  const size_t off_Kb  = E * sizeof(bf16);
  const size_t off_Vt  = off_Kb + E * sizeof(bf16);
  const size_t off_S   = off_Vt + E * sizeof(bf16);
  const size_t off_a1  = off_S + SE * sizeof(f16);
  const size_t need    = off_a1 + (size_t)BB * SS * sizeof(float);  // ~58.8 MB

  if (ws_size >= need) {
    char* ws = (char*)d_ws;
    bf16*  Qb  = (bf16*)ws;
    bf16*  Kb  = (bf16*)(ws + off_Kb);
    bf16*  Vt  = (bf16*)(ws + off_Vt);
    f16*   Sp  = (f16*)(ws + off_S);
    float* a1p = (float*)(ws + off_a1);

    prep_kernel<<<2048 + 1024, 256, 0, stream>>>(Q, K, V, Qb, Kb, Vt);
    qk_gemm_kernel<<<dim3(SS / 128, SS / 256, BB), 256, 0, stream>>>(Qb, Kb, Sp);
    stats_kernel<<<dim3(SS, BB), 256, 0, stream>>>(Sp, a1p);
    pv_fused_kernel<<<dim3(SS / 128, DD / 64, BB), 256, 0, stream>>>(Sp, Vt, a1p, out);
  } else {
    nm_attn_kernel<<<dim3(SS / 32, BB), dim3(256, 1, 1), 0, stream>>>(Q, K, V, out);
  }
}

// Round 3
// 179.774 us; speedup vs baseline: 1.1435x; 1.1435x over previous
//
#include <hip/hip_runtime.h>

// NeuromodulatedAttention — MI355X (gfx950), round 10
//
// ALGEBRA: (1) dopamine/serotonin "mod" is a per-row constant added before the
// per-row mean/std normalization -> cancels exactly (both MLPs are dead code).
// (2) the mean subtraction is a per-row constant inside softmax -> also cancels.
// Effective:  out = softmax( S * istd_row ) @ V,
//   S = Q K^T / sqrt(512),  istd_row = 1/(std(S_row, ddof=1) + 1e-6).
//
// Round-10 delta vs round 9 (205.6us; pv_fused 70.7us @ VALUBusy 63% / MfmaUtil
// 9.5% -> exp work was replicated 8x across dt-blocks = ~30us redundant VALU):
//   * smpv_kernel: fused exp+PV with exp computed once(x2) per S element.
//     Block = 64q x 256d x full-K (grid 32x2x4 = 256 = 1/CU exactly). 8 waves:
//     4 d-waves x 2 k-waves (8 ds_read : 8 MFMA), k-halves merged through LDS.
//     Per-CU traffic: 1MB Vt-slice (L2-resident; bid%8 XCD decode pins one
//     (dt,b) slice per XCD) + 0.5MB S. Double-buffered LDS, __syncthreads/iter.
//   * stats_kernel (r9, proven), qk/prep/fallback byte-identical to round 8.

#define BB 4
#define SS 2048
#define DD 512
#define SCALE 0.044194173824159216f  // 1/sqrt(512)
#define LOG2E 1.4426950408889634f

typedef __bf16 bf16;
typedef _Float16 f16;
typedef bf16 bf16x2 __attribute__((ext_vector_type(2)));
typedef bf16 bf16x4 __attribute__((ext_vector_type(4)));
typedef bf16 bf16x8 __attribute__((ext_vector_type(8)));
typedef f16  f16x8  __attribute__((ext_vector_type(8)));
typedef float f32x16 __attribute__((ext_vector_type(16)));

// async 16B/lane global->LDS; LDS dest = wave-uniform base + lane*16.
__device__ __forceinline__ void gload_lds16(const bf16* g, bf16* l) {
  __builtin_amdgcn_global_load_lds(
      (const __attribute__((address_space(1))) void*)g,
      (__attribute__((address_space(3))) void*)l, 16, 0, 0);
}

// ---------------- K1: prep = cast Q,K (bf16) + transpose V (bf16 [b][d][s]) ----

__global__ void prep_kernel(const float* __restrict__ Q, const float* __restrict__ K,
                            const float* __restrict__ V,
                            bf16* __restrict__ Qb, bf16* __restrict__ Kb,
                            bf16* __restrict__ Vt) {
  __shared__ bf16 tile[64][80];
  const int bx = blockIdx.x;
  const int t = threadIdx.x;
  if (bx < 2048) {
    // cast 8 elems of Q and K per thread
    size_t i = ((size_t)bx * 256 + t) * 8;
    float4 a0 = *(const float4*)(Q + i);
    float4 a1 = *(const float4*)(Q + i + 4);
    bf16x8 qa = { (bf16)a0.x, (bf16)a0.y, (bf16)a0.z, (bf16)a0.w,
                  (bf16)a1.x, (bf16)a1.y, (bf16)a1.z, (bf16)a1.w };
    *(bf16x8*)(Qb + i) = qa;
    float4 b0 = *(const float4*)(K + i);
    float4 b1 = *(const float4*)(K + i + 4);
    bf16x8 ka = { (bf16)b0.x, (bf16)b0.y, (bf16)b0.z, (bf16)b0.w,
                  (bf16)b1.x, (bf16)b1.y, (bf16)b1.z, (bf16)b1.w };
    *(bf16x8*)(Kb + i) = ka;
  } else {
    // V transpose, 64x64 tile
    const int tt = bx - 2048;
    const int s0 = (tt & 31) * 64, d0 = ((tt >> 5) & 7) * 64, b = tt >> 8;
    const int r16 = t >> 4;
    const int c4  = (t & 15) * 4;
#pragma unroll
    for (int i = 0; i < 4; ++i) {
      int r = i * 16 + r16;
      float4 v = *(const float4*)&V[((size_t)b * SS + s0 + r) * DD + d0 + c4];
      tile[c4 + 0][r] = (bf16)v.x;
      tile[c4 + 1][r] = (bf16)v.y;
      tile[c4 + 2][r] = (bf16)v.z;
      tile[c4 + 3][r] = (bf16)v.w;
    }
    __syncthreads();
    const int dr8 = t >> 3;
    const int sc8 = (t & 7) * 8;
#pragma unroll
    for (int i = 0; i < 2; ++i) {
      int dr = i * 32 + dr8;
      bf16x8 o = *(const bf16x8*)&tile[dr][sc8];
      *(bf16x8*)&Vt[((size_t)b * DD + d0 + dr) * SS + s0 + sc8] = o;
    }
  }
}

// ---------------- K2: QK^T GEMM -> S f16 (unchanged from round 8) ----------------
// grid (16 qt, 8 kt-pair, 4 b), 256 thr (4 waves). Each block: 128q x 256k
// (two 128x128 k-tiles sharing one staged A tile). BK=64 (8 iters).
// Wave (wq=w&1, wn=w>>1) owns the 64x64 quadrant of each 128x128 sub-tile.
// LDS rows 128B, chunk slot s of row r holds global chunk s^(r&7).

__launch_bounds__(256, 2)
__global__ void qk_gemm_kernel(const bf16* __restrict__ Qb, const bf16* __restrict__ Kb,
                               f16* __restrict__ Sp) {
  __shared__ bf16 At[128 * 64];
  __shared__ bf16 Bt[2][128 * 64];

  const int tid  = threadIdx.x;
  const int w    = tid >> 6;
  const int lane = tid & 63;
  const int l31  = lane & 31;
  const int lh   = lane >> 5;
  const int qt = blockIdx.x, kt2 = blockIdx.y, b = blockIdx.z;
  const int q0 = qt * 128, k0 = kt2 * 256;
  const int wq = w & 1, wn = w >> 1;
  const int m0 = wq * 64, n0 = wn * 64;

  const int srow = lane >> 3;          // row within 8-row staging group
  const int sg   = (lane & 7) ^ srow;  // swizzled global chunk index
  const bf16* gA = Qb + ((size_t)b * SS + q0) * DD;
  const bf16* gB = Kb + ((size_t)b * SS + k0) * DD;

  f32x16 acc[2][4];                    // [k-tile half][2*rowhalf + colhalf]
#pragma unroll
  for (int h = 0; h < 2; ++h)
#pragma unroll
    for (int u = 0; u < 4; ++u) acc[h][u] = (f32x16){};

  for (int dc = 0; dc < DD; dc += 64) {
    __syncthreads();
#pragma unroll
    for (int j = 0; j < 4; ++j) {
      int row = w * 32 + j * 8 + srow;
      gload_lds16(gA + (size_t)row * DD + dc + sg * 8, At + (w * 32 + j * 8) * 64);
      gload_lds16(gB + (size_t)row * DD + dc + sg * 8, Bt[0] + (w * 32 + j * 8) * 64);
      gload_lds16(gB + (size_t)(128 + row) * DD + dc + sg * 8,
                  Bt[1] + (w * 32 + j * 8) * 64);
    }
    __syncthreads();
#pragma unroll
    for (int kk = 0; kk < 4; ++kk) {
      int c = kk * 2 + lh;
      int ra0 = m0 + l31, ra1 = m0 + 32 + l31;
      int rb0 = n0 + l31, rb1 = n0 + 32 + l31;
      bf16x8 a0 = *(const bf16x8*)&At[ra0 * 64 + ((c ^ (ra0 & 7)) << 3)];
      bf16x8 a1 = *(const bf16x8*)&At[ra1 * 64 + ((c ^ (ra1 & 7)) << 3)];
#pragma unroll
      for (int h = 0; h < 2; ++h) {
        bf16x8 b0 = *(const bf16x8*)&Bt[h][rb0 * 64 + ((c ^ (rb0 & 7)) << 3)];
        bf16x8 b1 = *(const bf16x8*)&Bt[h][rb1 * 64 + ((c ^ (rb1 & 7)) << 3)];
        acc[h][0] = __builtin_amdgcn_mfma_f32_32x32x16_bf16(a0, b0, acc[h][0], 0, 0, 0);
        acc[h][1] = __builtin_amdgcn_mfma_f32_32x32x16_bf16(a0, b1, acc[h][1], 0, 0, 0);
        acc[h][2] = __builtin_amdgcn_mfma_f32_32x32x16_bf16(a1, b0, acc[h][2], 0, 0, 0);
        acc[h][3] = __builtin_amdgcn_mfma_f32_32x32x16_bf16(a1, b1, acc[h][3], 0, 0, 0);
      }
    }
  }

  int qrow[16];
#pragma unroll
  for (int r = 0; r < 16; ++r) qrow[r] = (r & 3) + 8 * (r >> 2) + 4 * lh;

  // epilogue: pure f16 stores (stats are computed by stats_kernel from S)
#pragma unroll
  for (int h = 0; h < 2; ++h) {
    f16* Sb = Sp + ((size_t)b * SS + q0) * SS + k0 + h * 128 + n0;
#pragma unroll
    for (int i = 0; i < 2; ++i) {
      const f32x16& A0 = acc[h][i * 2 + 0];
      const f32x16& A1 = acc[h][i * 2 + 1];
#pragma unroll
      for (int r = 0; r < 16; ++r) {
        f16* Sr = Sb + (size_t)(m0 + i * 32 + qrow[r]) * SS;
        Sr[l31]      = (f16)(A0[r] * SCALE);
        Sr[32 + l31] = (f16)(A1[r] * SCALE);
      }
    }
  }
}

// ---------------- K3: stats (sum/sumsq -> a1 per row), no exp, no P ----------------
// grid (2048, 4), 256 thr; block = one q-row (2048 f16, 8/thread).

__global__ void stats_kernel(const f16* __restrict__ Sp, float* __restrict__ a1out) {
  __shared__ float redS[4], redQ[4];
  const int row = blockIdx.x, b = blockIdx.y;
  const int tid = threadIdx.x;
  const int lane = tid & 63, w = tid >> 6;
  const size_t base = ((size_t)b * SS + row) * SS;

  f16x8 hv = *(const f16x8*)&Sp[base + tid * 8];
  float s = 0.f, q = 0.f;
#pragma unroll
  for (int j = 0; j < 8; ++j) {
    float v = (float)hv[j];
    s += v;
    q += v * v;
  }
#pragma unroll
  for (int m = 32; m >= 1; m >>= 1) { s += __shfl_xor(s, m); q += __shfl_xor(q, m); }
  if (lane == 0) { redS[w] = s; redQ[w] = q; }
  __syncthreads();
  if (tid == 0) {
    s = redS[0] + redS[1] + redS[2] + redS[3];
    q = redQ[0] + redQ[1] + redQ[2] + redQ[3];
    float mean = s * (1.0f / 2048.0f);
    float var  = (q - 2048.0f * mean * mean) * (1.0f / 2047.0f);
    var = fmaxf(var, 0.0f);
    // p = exp((s-mean)*istd); per-row exp(-mean*istd) cancels in softmax.
    a1out[b * SS + row] = LOG2E / (sqrtf(var) + 1e-6f);
  }
}

// ---------------- K4: fused softmax + PV GEMM -> out (fp32) ----------------
// grid: 256 blocks (bid: dt=bid&1, b=(bid>>1)&3, qt2=bid>>3) = 1 block/CU;
// with HW round-robin XCD dispatch, each XCD sees one fixed (dt,b) -> its 1MB
// Vt slice stays L2-resident. 512 thr (8 waves: wd=w&3 d-tile, wk=w>>2 k-half).
// Block tile: 64q x 256d, BK=64 (32 iters), double-buffered LDS.
// Wave tile: 64q x 64d x 32k-half -> 8 ds_read_b128 : 8 MFMA per iter.
// A-path: thread owns (row r=tid>>3, chunk c=tid&7): load S f16x8 -> exp2(v*a1)
// -> bf16 -> ds_write At[o][r][c^(r&7)] (XOR-swizzled rows, 128B each).
// den accumulated per-thread from the bf16-rounded p (same values PV uses),
// reduced via LDS at the end. k-halves merged through LDS (Bt reused as f32
// scratch). exp per element done once per dt (x2 total, vs x8 in round 9).

__launch_bounds__(512)
__global__ void smpv_kernel(const f16* __restrict__ Sp, const bf16* __restrict__ Vt,
                            const float* __restrict__ a1p, float* __restrict__ out) {
  __shared__ bf16 At[2][64 * 64];    // 16 KB
  __shared__ bf16 Bt[2][256 * 64];   // 64 KB (reused as f32[64][256] at end)
  __shared__ float denp[512];
  __shared__ float dinv[64];

  const int tid  = threadIdx.x;
  const int w    = tid >> 6;
  const int lane = tid & 63;
  const int l31  = lane & 31;
  const int lh   = lane >> 5;
  const int wd   = w & 3, wk = w >> 2;
  const int bid  = blockIdx.x;
  const int dt   = bid & 1, b = (bid >> 1) & 3, qt2 = bid >> 3;
  const int q0   = qt2 * 64, d0 = dt * 256;

  // exp staging map: thread owns row r (of 64), chunk c (of 8, 8 f16 each)
  const int er = tid >> 3, ec = tid & 7;
  const float a1 = a1p[b * SS + q0 + er];
  const f16* gS = Sp + ((size_t)b * SS + q0 + er) * SS + ec * 8;
  const int aoff = er * 64 + ((ec ^ (er & 7)) << 3);

  // B staging map: wave w round j covers Vt rows [w*32+j*8, +8)
  const int brow = w * 32 + (lane >> 3);           // + j*8
  const int bsw  = ((lane & 7) ^ (brow & 7)) * 8;  // swizzle const per lane
  const bf16* gB = Vt + ((size_t)b * DD + d0) * SS;
  const bf16* srcB0 = gB + (size_t)(brow + 0) * SS + bsw;
  const bf16* srcB1 = gB + (size_t)(brow + 8) * SS + bsw;
  const bf16* srcB2 = gB + (size_t)(brow + 16) * SS + bsw;
  const bf16* srcB3 = gB + (size_t)(brow + 24) * SS + bsw;

  f32x16 acc[2][2];
#pragma unroll
  for (int i = 0; i < 2; ++i)
#pragma unroll
    for (int j = 0; j < 2; ++j) acc[i][j] = (f32x16){};

  float loc = 0.f;   // this thread's share of den[er]

#define EXPWRITE(o, h)                                            \
  {                                                               \
    bf16x8 pb;                                                    \
    _Pragma("unroll")                                             \
    for (int u = 0; u < 8; ++u) {                                 \
      float p = exp2f((float)(h)[u] * a1);                        \
      bf16 pc = (bf16)p;                                          \
      pb[u] = pc;                                                 \
      loc += (float)pc;                                           \
    }                                                             \
    *(bf16x8*)&At[o][aoff] = pb;                                  \
  }

#define STAGEB(o, kc)                                             \
  {                                                               \
    bf16* Bo = Bt[o] + (w * 32) * 64;                             \
    gload_lds16(srcB0 + (kc), Bo);                                \
    gload_lds16(srcB1 + (kc), Bo + 8 * 64);                       \
    gload_lds16(srcB2 + (kc), Bo + 16 * 64);                      \
    gload_lds16(srcB3 + (kc), Bo + 24 * 64);                      \
  }

  // prologue: stage tile 0 into buffer 0, prefetch S(1)
  f16x8 hv = *(const f16x8*)gS;
  EXPWRITE(0, hv)
  STAGEB(0, 0)
  hv = *(const f16x8*)(gS + 64);
  __syncthreads();

  for (int t = 0; t < 32; ++t) {
    const int cur = t & 1, o = cur ^ 1;
    if (t < 31) {
      EXPWRITE(o, hv)
      STAGEB(o, (t + 1) * 64)
    }
    if (t < 30) hv = *(const f16x8*)(gS + (t + 2) * 64);

#pragma unroll
    for (int kk = 0; kk < 2; ++kk) {
      const int slot = (wk * 2 + kk) * 2 + lh;     // 0..7
      const int ra0 = l31, ra1 = 32 + l31;
      const int rb0 = wd * 64 + l31, rb1 = wd * 64 + 32 + l31;
      bf16x8 a0 = *(const bf16x8*)&At[cur][ra0 * 64 + ((slot ^ (ra0 & 7)) << 3)];
      bf16x8 a1f = *(const bf16x8*)&At[cur][ra1 * 64 + ((slot ^ (ra1 & 7)) << 3)];
      bf16x8 b0 = *(const bf16x8*)&Bt[cur][rb0 * 64 + ((slot ^ (rb0 & 7)) << 3)];
      bf16x8 b1 = *(const bf16x8*)&Bt[cur][rb1 * 64 + ((slot ^ (rb1 & 7)) << 3)];
      acc[0][0] = __builtin_amdgcn_mfma_f32_32x32x16_bf16(a0, b0, acc[0][0], 0, 0, 0);
      acc[0][1] = __builtin_amdgcn_mfma_f32_32x32x16_bf16(a0, b1, acc[0][1], 0, 0, 0);
      acc[1][0] = __builtin_amdgcn_mfma_f32_32x32x16_bf16(a1f, b0, acc[1][0], 0, 0, 0);
      acc[1][1] = __builtin_amdgcn_mfma_f32_32x32x16_bf16(a1f, b1, acc[1][1], 0, 0, 0);
    }
    __syncthreads();
  }

  // den partials + k-half merge
  denp[tid] = loc;
  int qrow[16];
#pragma unroll
  for (int r = 0; r < 16; ++r) qrow[r] = (r & 3) + 8 * (r >> 2) + 4 * lh;

  float* Lred = (float*)&Bt[0][0];   // 64x256 f32 = 64 KB, exactly Bt
  if (wk == 1) {
#pragma unroll
    for (int i = 0; i < 2; ++i)
#pragma unroll
      for (int j = 0; j < 2; ++j)
#pragma unroll
        for (int r = 0; r < 16; ++r) {
          int row = i * 32 + qrow[r];
          Lred[row * 256 + wd * 64 + j * 32 + l31] = acc[i][j][r];
        }
  }
  __syncthreads();
  if (tid < 64) {
    float s = 0.f;
#pragma unroll
    for (int c = 0; c < 8; ++c) s += denp[tid * 8 + c];
    dinv[tid] = 1.0f / s;
  }
  __syncthreads();
  if (wk == 0) {
    float* Ob = out + ((size_t)b * SS + q0) * DD + d0 + wd * 64;
#pragma unroll
    for (int i = 0; i < 2; ++i)
#pragma unroll
      for (int j = 0; j < 2; ++j)
#pragma unroll
        for (int r = 0; r < 16; ++r) {
          int row = i * 32 + qrow[r];
          Ob[(size_t)row * DD + j * 32 + l31] =
              (acc[i][j][r] + Lred[row * 256 + wd * 64 + j * 32 + l31]) * dinv[row];
        }
  }
#undef EXPWRITE
#undef STAGEB
}

// ---------------- fallback (round-1 kernel, zero workspace) ----------------

#define QS_STRIDE 520
#define KS_STRIDE 72
#define VT_STRIDE 18
#define PS_STRIDE 136

__device__ __forceinline__ f32x16 qk_tile(const float* __restrict__ Kb,
                                          const bf16* __restrict__ Qsl,
                                          bf16* __restrict__ KVw,
                                          int l31, int lh8, int lane) {
  f32x16 acc = {};
  for (int dc = 0; dc < DD; dc += 64) {
#pragma unroll
    for (int i = 0; i < 8; ++i) {
      int f = i * 64 + lane;
      int row = f >> 4;
      int c4 = (f & 15) * 4;
      float4 v = *(const float4*)(Kb + row * DD + dc + c4);
      bf16x4 h = { (bf16)v.x, (bf16)v.y, (bf16)v.z, (bf16)v.w };
      *(bf16x4*)&KVw[row * KS_STRIDE + c4] = h;
    }
#pragma unroll
    for (int ks = 0; ks < 4; ++ks) {
      bf16x8 a  = *(const bf16x8*)&Qsl[l31 * QS_STRIDE + dc + ks * 16 + lh8];
      bf16x8 bb = *(const bf16x8*)&KVw[l31 * KS_STRIDE + ks * 16 + lh8];
      acc = __builtin_amdgcn_mfma_f32_32x32x16_bf16(a, bb, acc, 0, 0, 0);
    }
  }
  return acc;
}

__launch_bounds__(256, 1)
__global__ void nm_attn_kernel(const float* __restrict__ Qp,
                               const float* __restrict__ Kp,
                               const float* __restrict__ Vp,
                               float* __restrict__ Op) {
  __shared__ bf16 Qs[32 * QS_STRIDE];
  __shared__ bf16 KVu[4][32 * KS_STRIDE];
  __shared__ bf16 Psl[32 * PS_STRIDE];
  __shared__ float redA[4][32];
  __shared__ float redB[4][32];
  __shared__ float a0v[32], a1v[32], idv[32];

  const int tid  = threadIdx.x;
  const int w    = tid >> 6;
  const int lane = tid & 63;
  const int l31  = lane & 31;
  const int lh8  = (lane >> 5) * 8;
  const int b    = blockIdx.y;
  const int q0   = blockIdx.x * 32;

  {
    const float* Qbase = Qp + (size_t)(b * SS + q0) * DD;
#pragma unroll
    for (int i = 0; i < 16; ++i) {
      int f = i * 256 + tid;
      int row = f >> 7;
      int c4 = (f & 127) * 4;
      float4 v = *(const float4*)(Qbase + row * DD + c4);
      bf16x4 h = { (bf16)v.x, (bf16)v.y, (bf16)v.z, (bf16)v.w };
      *(bf16x4*)&Qs[row * QS_STRIDE + c4] = h;
    }
  }
  __syncthreads();

  int qrow[16];
#pragma unroll
  for (int r = 0; r < 16; ++r) qrow[r] = (r & 3) + 8 * (r >> 2) + 4 * (lane >> 5);

  float sumv[16], sqv[16];
#pragma unroll
  for (int r = 0; r < 16; ++r) { sumv[r] = 0.f; sqv[r] = 0.f; }

  for (int kt = 0; kt < 16; ++kt) {
    const float* Kb = Kp + (size_t)(b * SS + kt * 128 + w * 32) * DD;
    f32x16 acc = qk_tile(Kb, Qs, KVu[w], l31, lh8, lane);
#pragma unroll
    for (int r = 0; r < 16; ++r) {
      float s = acc[r] * SCALE;
      sumv[r] += s;
      sqv[r]  += s * s;
    }
  }

#pragma unroll
  for (int r = 0; r < 16; ++r) {
    float v1 = sumv[r], v2 = sqv[r];
#pragma unroll
    for (int m = 16; m >= 1; m >>= 1) {
      v1 += __shfl_xor(v1, m);
      v2 += __shfl_xor(v2, m);
    }
    if (l31 == 0) { redA[w][qrow[r]] = v1; redB[w][qrow[r]] = v2; }
  }
  __syncthreads();
  if (tid < 32) {
    float s  = redA[0][tid] + redA[1][tid] + redA[2][tid] + redA[3][tid];
    float sq = redB[0][tid] + redB[1][tid] + redB[2][tid] + redB[3][tid];
    float mean = s * (1.0f / 2048.0f);
    float var = (sq - 2048.0f * mean * mean) * (1.0f / 2047.0f);
    var = fmaxf(var, 0.0f);
    float istd = 1.0f / (sqrtf(var) + 1e-6f);
    a1v[tid] = istd * LOG2E;
    a0v[tid] = -mean * istd * LOG2E;
  }
  __syncthreads();

  float a0r[16], a1r[16], den[16];
#pragma unroll
  for (int r = 0; r < 16; ++r) {
    a0r[r] = a0v[qrow[r]];
    a1r[r] = a1v[qrow[r]];
    den[r] = 0.f;
  }

  f32x16 Oa[4] = {};

  for (int kt = 0; kt < 16; ++kt) {
    const float* Kb = Kp + (size_t)(b * SS + kt * 128 + w * 32) * DD;
    f32x16 acc = qk_tile(Kb, Qs, KVu[w], l31, lh8, lane);

    __syncthreads();
#pragma unroll
    for (int r = 0; r < 16; ++r) {
      float s = acc[r] * SCALE;
      float p = exp2f(fmaf(s, a1r[r], a0r[r]));
      den[r] += p;
      Psl[qrow[r] * PS_STRIDE + w * 32 + l31] = (bf16)p;
    }
    __syncthreads();

    const float* Vb = Vp + (size_t)(b * SS + kt * 128) * DD + w * 128 + 2 * lane;
    bf16* Vts = KVu[w];
    const int d0 = 2 * lane;
    for (int ks2 = 0; ks2 < 8; ++ks2) {
      const float* Vk = Vb + ks2 * 16 * DD;
#pragma unroll
      for (int i = 0; i < 8; ++i) {
        float2 va = *(const float2*)(Vk + (2 * i) * DD);
        float2 vc = *(const float2*)(Vk + (2 * i + 1) * DD);
        bf16x2 h0 = { (bf16)va.x, (bf16)vc.x };
        bf16x2 h1 = { (bf16)va.y, (bf16)vc.y };
        *(bf16x2*)&Vts[d0 * VT_STRIDE + 2 * i] = h0;
        *(bf16x2*)&Vts[(d0 + 1) * VT_STRIDE + 2 * i] = h1;
      }
      bf16x8 aP = *(const bf16x8*)&Psl[l31 * PS_STRIDE + ks2 * 16 + lh8];
#pragma unroll
      for (int dt = 0; dt < 4; ++dt) {
        const bf16* vr = &Vts[(dt * 32 + l31) * VT_STRIDE + lh8];
        bf16x2 e0 = *(const bf16x2*)(vr + 0);
        bf16x2 e1 = *(const bf16x2*)(vr + 2);
        bf16x2 e2 = *(const bf16x2*)(vr + 4);
        bf16x2 e3 = *(const bf16x2*)(vr + 6);
        bf16x8 bV = { e0.x, e0.y, e1.x, e1.y, e2.x, e2.y, e3.x, e3.y };
        Oa[dt] = __builtin_amdgcn_mfma_f32_32x32x16_bf16(aP, bV, Oa[dt], 0, 0, 0);
      }
    }
  }

#pragma unroll
  for (int r = 0; r < 16; ++r) {
    float v1 = den[r];
#pragma unroll
    for (int m = 16; m >= 1; m >>= 1) v1 += __shfl_xor(v1, m);
    if (l31 == 0) redA[w][qrow[r]] = v1;
  }
  __syncthreads();
  if (tid < 32) {
    float t = redA[0][tid] + redA[1][tid] + redA[2][tid] + redA[3][tid];
    idv[tid] = 1.0f / t;
  }
  __syncthreads();

  float idr[16];
#pragma unroll
  for (int r = 0; r < 16; ++r) idr[r] = idv[qrow[r]];

  float* Ob = Op + (size_t)(b * SS + q0) * DD + w * 128;
#pragma unroll
  for (int dt = 0; dt < 4; ++dt) {
#pragma unroll
    for (int r = 0; r < 16; ++r) {
      Ob[qrow[r] * DD + dt * 32 + l31] = Oa[dt][r] * idr[r];
    }
  }
}

// ---------------- launcher ----------------

extern "C" void kernel_launch(void* const* d_in, const int* in_sizes, int n_in,
                              void* d_out, int out_size, void* d_ws, size_t ws_size,
                              hipStream_t stream) {
  const float* Q = (const float*)d_in[0];
  const float* K = (const float*)d_in[1];
  const float* V = (const float*)d_in[2];
  float* out = (float*)d_out;
  (void)in_sizes; (void)n_in; (void)out_size;

  const size_t E  = (size_t)BB * SS * DD;   // 4,194,304 elems / tensor
  const size_t SE = (size_t)BB * SS * SS;   // 16,777,216 score elems

  // ws layout: [Qb bf16 E][Kb bf16 E][Vt bf16 E][S f16 SE][a1 B*S f32]
  const size_t off_Kb  = E * sizeof(bf16);
  const size_t off_Vt  = off_Kb + E * sizeof(bf16);
  const size_t off_S   = off_Vt + E * sizeof(bf16);
  const size_t off_a1  = off_S + SE * sizeof(f16);
  const size_t need    = off_a1 + (size_t)BB * SS * sizeof(float);  // ~58.8 MB

  if (ws_size >= need) {
    char* ws = (char*)d_ws;
    bf16*  Qb  = (bf16*)ws;
    bf16*  Kb  = (bf16*)(ws + off_Kb);
    bf16*  Vt  = (bf16*)(ws + off_Vt);
    f16*   Sp  = (f16*)(ws + off_S);
    float* a1p = (float*)(ws + off_a1);

    prep_kernel<<<2048 + 1024, 256, 0, stream>>>(Q, K, V, Qb, Kb, Vt);
    qk_gemm_kernel<<<dim3(SS / 128, SS / 256, BB), 256, 0, stream>>>(Qb, Kb, Sp);
    stats_kernel<<<dim3(SS, BB), 256, 0, stream>>>(Sp, a1p);
    smpv_kernel<<<256, 512, 0, stream>>>(Sp, Vt, a1p, out);
  } else {
    nm_attn_kernel<<<dim3(SS / 32, BB), dim3(256, 1, 1), 0, stream>>>(Q, K, V, out);
  }
}

// Round 4
// 179.529 us; speedup vs baseline: 1.1450x; 1.0014x over previous
//
#include <hip/hip_runtime.h>

// NeuromodulatedAttention — MI355X (gfx950), round 11
//
// ALGEBRA: (1) dopamine/serotonin "mod" is a per-row constant added before the
// per-row mean/std normalization -> cancels exactly (both MLPs are dead code).
// (2) the mean subtraction is a per-row constant inside softmax -> also cancels.
// Effective:  out = softmax( S * istd_row ) @ V,
//   S = Q K^T / sqrt(512),  istd_row = 1/(std(S_row, ddof=1) + 1e-6).
//
// Round-11 delta vs round 10 (179.8us; smpv 40.8us @ MfmaUtil 14.5 / VALUBusy 31
// / occ 17 = latency-bound; 1 block/CU + __syncthreads => vmcnt(0) drain every
// iter right after issuing next-tile loads -> full L2 latency exposed 32x):
//   * smpv_kernel: counted-vmcnt raw-barrier pipeline (T3/T4). Per iter:
//     STAGEB(t+1) -> EXPWRITE(t+1) (hv auto-wait retires tile-t loads, keeps
//     the 4 just-issued in flight) -> S prefetch (t+2) -> vmcnt(5)+lgkmcnt(0)
//     -> s_barrier -> MFMA(t) -> s_barrier. No vmcnt(0) in the main loop;
//     B loads get ~1 iter of lead, S loads 2 iters.
//   * qk / prep / stats / fallback: byte-identical to round 10.

#define BB 4
#define SS 2048
#define DD 512
#define SCALE 0.044194173824159216f  // 1/sqrt(512)
#define LOG2E 1.4426950408889634f

typedef __bf16 bf16;
typedef _Float16 f16;
typedef bf16 bf16x2 __attribute__((ext_vector_type(2)));
typedef bf16 bf16x4 __attribute__((ext_vector_type(4)));
typedef bf16 bf16x8 __attribute__((ext_vector_type(8)));
typedef f16  f16x8  __attribute__((ext_vector_type(8)));
typedef float f32x16 __attribute__((ext_vector_type(16)));

// async 16B/lane global->LDS; LDS dest = wave-uniform base + lane*16.
__device__ __forceinline__ void gload_lds16(const bf16* g, bf16* l) {
  __builtin_amdgcn_global_load_lds(
      (const __attribute__((address_space(1))) void*)g,
      (__attribute__((address_space(3))) void*)l, 16, 0, 0);
}

// ---------------- K1: prep = cast Q,K (bf16) + transpose V (bf16 [b][d][s]) ----

__global__ void prep_kernel(const float* __restrict__ Q, const float* __restrict__ K,
                            const float* __restrict__ V,
                            bf16* __restrict__ Qb, bf16* __restrict__ Kb,
                            bf16* __restrict__ Vt) {
  __shared__ bf16 tile[64][80];
  const int bx = blockIdx.x;
  const int t = threadIdx.x;
  if (bx < 2048) {
    // cast 8 elems of Q and K per thread
    size_t i = ((size_t)bx * 256 + t) * 8;
    float4 a0 = *(const float4*)(Q + i);
    float4 a1 = *(const float4*)(Q + i + 4);
    bf16x8 qa = { (bf16)a0.x, (bf16)a0.y, (bf16)a0.z, (bf16)a0.w,
                  (bf16)a1.x, (bf16)a1.y, (bf16)a1.z, (bf16)a1.w };
    *(bf16x8*)(Qb + i) = qa;
    float4 b0 = *(const float4*)(K + i);
    float4 b1 = *(const float4*)(K + i + 4);
    bf16x8 ka = { (bf16)b0.x, (bf16)b0.y, (bf16)b0.z, (bf16)b0.w,
                  (bf16)b1.x, (bf16)b1.y, (bf16)b1.z, (bf16)b1.w };
    *(bf16x8*)(Kb + i) = ka;
  } else {
    // V transpose, 64x64 tile
    const int tt = bx - 2048;
    const int s0 = (tt & 31) * 64, d0 = ((tt >> 5) & 7) * 64, b = tt >> 8;
    const int r16 = t >> 4;
    const int c4  = (t & 15) * 4;
#pragma unroll
    for (int i = 0; i < 4; ++i) {
      int r = i * 16 + r16;
      float4 v = *(const float4*)&V[((size_t)b * SS + s0 + r) * DD + d0 + c4];
      tile[c4 + 0][r] = (bf16)v.x;
      tile[c4 + 1][r] = (bf16)v.y;
      tile[c4 + 2][r] = (bf16)v.z;
      tile[c4 + 3][r] = (bf16)v.w;
    }
    __syncthreads();
    const int dr8 = t >> 3;
    const int sc8 = (t & 7) * 8;
#pragma unroll
    for (int i = 0; i < 2; ++i) {
      int dr = i * 32 + dr8;
      bf16x8 o = *(const bf16x8*)&tile[dr][sc8];
      *(bf16x8*)&Vt[((size_t)b * DD + d0 + dr) * SS + s0 + sc8] = o;
    }
  }
}

// ---------------- K2: QK^T GEMM -> S f16 (unchanged from round 8) ----------------
// grid (16 qt, 8 kt-pair, 4 b), 256 thr (4 waves). Each block: 128q x 256k
// (two 128x128 k-tiles sharing one staged A tile). BK=64 (8 iters).
// Wave (wq=w&1, wn=w>>1) owns the 64x64 quadrant of each 128x128 sub-tile.
// LDS rows 128B, chunk slot s of row r holds global chunk s^(r&7).

__launch_bounds__(256, 2)
__global__ void qk_gemm_kernel(const bf16* __restrict__ Qb, const bf16* __restrict__ Kb,
                               f16* __restrict__ Sp) {
  __shared__ bf16 At[128 * 64];
  __shared__ bf16 Bt[2][128 * 64];

  const int tid  = threadIdx.x;
  const int w    = tid >> 6;
  const int lane = tid & 63;
  const int l31  = lane & 31;
  const int lh   = lane >> 5;
  const int qt = blockIdx.x, kt2 = blockIdx.y, b = blockIdx.z;
  const int q0 = qt * 128, k0 = kt2 * 256;
  const int wq = w & 1, wn = w >> 1;
  const int m0 = wq * 64, n0 = wn * 64;

  const int srow = lane >> 3;          // row within 8-row staging group
  const int sg   = (lane & 7) ^ srow;  // swizzled global chunk index
  const bf16* gA = Qb + ((size_t)b * SS + q0) * DD;
  const bf16* gB = Kb + ((size_t)b * SS + k0) * DD;

  f32x16 acc[2][4];                    // [k-tile half][2*rowhalf + colhalf]
#pragma unroll
  for (int h = 0; h < 2; ++h)
#pragma unroll
    for (int u = 0; u < 4; ++u) acc[h][u] = (f32x16){};

  for (int dc = 0; dc < DD; dc += 64) {
    __syncthreads();
#pragma unroll
    for (int j = 0; j < 4; ++j) {
      int row = w * 32 + j * 8 + srow;
      gload_lds16(gA + (size_t)row * DD + dc + sg * 8, At + (w * 32 + j * 8) * 64);
      gload_lds16(gB + (size_t)row * DD + dc + sg * 8, Bt[0] + (w * 32 + j * 8) * 64);
      gload_lds16(gB + (size_t)(128 + row) * DD + dc + sg * 8,
                  Bt[1] + (w * 32 + j * 8) * 64);
    }
    __syncthreads();
#pragma unroll
    for (int kk = 0; kk < 4; ++kk) {
      int c = kk * 2 + lh;
      int ra0 = m0 + l31, ra1 = m0 + 32 + l31;
      int rb0 = n0 + l31, rb1 = n0 + 32 + l31;
      bf16x8 a0 = *(const bf16x8*)&At[ra0 * 64 + ((c ^ (ra0 & 7)) << 3)];
      bf16x8 a1 = *(const bf16x8*)&At[ra1 * 64 + ((c ^ (ra1 & 7)) << 3)];
#pragma unroll
      for (int h = 0; h < 2; ++h) {
        bf16x8 b0 = *(const bf16x8*)&Bt[h][rb0 * 64 + ((c ^ (rb0 & 7)) << 3)];
        bf16x8 b1 = *(const bf16x8*)&Bt[h][rb1 * 64 + ((c ^ (rb1 & 7)) << 3)];
        acc[h][0] = __builtin_amdgcn_mfma_f32_32x32x16_bf16(a0, b0, acc[h][0], 0, 0, 0);
        acc[h][1] = __builtin_amdgcn_mfma_f32_32x32x16_bf16(a0, b1, acc[h][1], 0, 0, 0);
        acc[h][2] = __builtin_amdgcn_mfma_f32_32x32x16_bf16(a1, b0, acc[h][2], 0, 0, 0);
        acc[h][3] = __builtin_amdgcn_mfma_f32_32x32x16_bf16(a1, b1, acc[h][3], 0, 0, 0);
      }
    }
  }

  int qrow[16];
#pragma unroll
  for (int r = 0; r < 16; ++r) qrow[r] = (r & 3) + 8 * (r >> 2) + 4 * lh;

  // epilogue: pure f16 stores (stats are computed by stats_kernel from S)
#pragma unroll
  for (int h = 0; h < 2; ++h) {
    f16* Sb = Sp + ((size_t)b * SS + q0) * SS + k0 + h * 128 + n0;
#pragma unroll
    for (int i = 0; i < 2; ++i) {
      const f32x16& A0 = acc[h][i * 2 + 0];
      const f32x16& A1 = acc[h][i * 2 + 1];
#pragma unroll
      for (int r = 0; r < 16; ++r) {
        f16* Sr = Sb + (size_t)(m0 + i * 32 + qrow[r]) * SS;
        Sr[l31]      = (f16)(A0[r] * SCALE);
        Sr[32 + l31] = (f16)(A1[r] * SCALE);
      }
    }
  }
}

// ---------------- K3: stats (sum/sumsq -> a1 per row), no exp, no P ----------------
// grid (2048, 4), 256 thr; block = one q-row (2048 f16, 8/thread).

__global__ void stats_kernel(const f16* __restrict__ Sp, float* __restrict__ a1out) {
  __shared__ float redS[4], redQ[4];
  const int row = blockIdx.x, b = blockIdx.y;
  const int tid = threadIdx.x;
  const int lane = tid & 63, w = tid >> 6;
  const size_t base = ((size_t)b * SS + row) * SS;

  f16x8 hv = *(const f16x8*)&Sp[base + tid * 8];
  float s = 0.f, q = 0.f;
#pragma unroll
  for (int j = 0; j < 8; ++j) {
    float v = (float)hv[j];
    s += v;
    q += v * v;
  }
#pragma unroll
  for (int m = 32; m >= 1; m >>= 1) { s += __shfl_xor(s, m); q += __shfl_xor(q, m); }
  if (lane == 0) { redS[w] = s; redQ[w] = q; }
  __syncthreads();
  if (tid == 0) {
    s = redS[0] + redS[1] + redS[2] + redS[3];
    q = redQ[0] + redQ[1] + redQ[2] + redQ[3];
    float mean = s * (1.0f / 2048.0f);
    float var  = (q - 2048.0f * mean * mean) * (1.0f / 2047.0f);
    var = fmaxf(var, 0.0f);
    // p = exp((s-mean)*istd); per-row exp(-mean*istd) cancels in softmax.
    a1out[b * SS + row] = LOG2E / (sqrtf(var) + 1e-6f);
  }
}

// ---------------- K4: fused softmax + PV GEMM -> out (fp32) ----------------
// grid: 256 blocks (bid: dt=bid&1, b=(bid>>1)&3, qt2=bid>>3) = 1 block/CU;
// 512 thr (8 waves: wd=w&3 d-tile, wk=w>>2 k-half). Block tile 64q x 256d,
// BK=64 (32 iters), double-buffered LDS.
// Counted-vmcnt raw-barrier pipeline (T3/T4): per iter issue STAGEB(t+1)
// (4 gload_lds) then EXPWRITE(t+1) (hv dep auto-wait retires tile-t's loads,
// keeps the new 4 in flight), prefetch S(t+2) to regs, then vmcnt(5)+lgkm(0),
// s_barrier, MFMA(t), s_barrier. No vmcnt(0) drain in the main loop.
// den accumulated per-thread from the bf16-rounded p (same values PV uses);
// k-halves merged through LDS (Bt reused as f32 scratch).

__launch_bounds__(512)
__global__ void smpv_kernel(const f16* __restrict__ Sp, const bf16* __restrict__ Vt,
                            const float* __restrict__ a1p, float* __restrict__ out) {
  __shared__ bf16 At[2][64 * 64];    // 16 KB
  __shared__ bf16 Bt[2][256 * 64];   // 64 KB (reused as f32[64][256] at end)
  __shared__ float denp[512];
  __shared__ float dinv[64];

  const int tid  = threadIdx.x;
  const int w    = tid >> 6;
  const int lane = tid & 63;
  const int l31  = lane & 31;
  const int lh   = lane >> 5;
  const int wd   = w & 3, wk = w >> 2;
  const int bid  = blockIdx.x;
  const int dt   = bid & 1, b = (bid >> 1) & 3, qt2 = bid >> 3;
  const int q0   = qt2 * 64, d0 = dt * 256;

  // exp staging map: thread owns row r (of 64), chunk c (of 8, 8 f16 each)
  const int er = tid >> 3, ec = tid & 7;
  const float a1 = a1p[b * SS + q0 + er];
  const f16* gS = Sp + ((size_t)b * SS + q0 + er) * SS + ec * 8;
  const int aoff = er * 64 + ((ec ^ (er & 7)) << 3);

  // B staging map: wave w round j covers Vt rows [w*32+j*8, +8)
  const int brow = w * 32 + (lane >> 3);           // + j*8
  const int bsw  = ((lane & 7) ^ (brow & 7)) * 8;  // swizzle const per lane
  const bf16* gB = Vt + ((size_t)b * DD + d0) * SS;
  const bf16* srcB0 = gB + (size_t)(brow + 0) * SS + bsw;
  const bf16* srcB1 = gB + (size_t)(brow + 8) * SS + bsw;
  const bf16* srcB2 = gB + (size_t)(brow + 16) * SS + bsw;
  const bf16* srcB3 = gB + (size_t)(brow + 24) * SS + bsw;

  f32x16 acc[2][2];
#pragma unroll
  for (int i = 0; i < 2; ++i)
#pragma unroll
    for (int j = 0; j < 2; ++j) acc[i][j] = (f32x16){};

  float loc = 0.f;   // this thread's share of den[er]

#define EXPWRITE(o, h)                                            \
  {                                                               \
    bf16x8 pb;                                                    \
    _Pragma("unroll")                                             \
    for (int u = 0; u < 8; ++u) {                                 \
      float p = exp2f((float)(h)[u] * a1);                        \
      bf16 pc = (bf16)p;                                          \
      pb[u] = pc;                                                 \
      loc += (float)pc;                                           \
    }                                                             \
    *(bf16x8*)&At[o][aoff] = pb;                                  \
  }

#define STAGEB(o, kc)                                             \
  {                                                               \
    bf16* Bo = Bt[o] + (w * 32) * 64;                             \
    gload_lds16(srcB0 + (kc), Bo);                                \
    gload_lds16(srcB1 + (kc), Bo + 8 * 64);                       \
    gload_lds16(srcB2 + (kc), Bo + 16 * 64);                      \
    gload_lds16(srcB3 + (kc), Bo + 24 * 64);                      \
  }

  // prologue: stage tile 0 into buffer 0, prefetch S(1)
  f16x8 hv = *(const f16x8*)gS;     // S(0)
  STAGEB(0, 0)                      // 4 loads in flight
  EXPWRITE(0, hv)                   // waits S(0) only (issued before STAGEB)
  hv = *(const f16x8*)(gS + 64);    // S(1)

  for (int t = 0; t < 32; ++t) {
    const int cur = t & 1, o = cur ^ 1;
    if (t < 31) {
      STAGEB(o, (t + 1) * 64)       // 4 gload_lds for tile t+1 (stay in flight)
      EXPWRITE(o, hv)               // hv=S(t+1); auto-wait retires tile-t's 4
    }
    if (t < 30) hv = *(const f16x8*)(gS + (t + 2) * 64);  // S(t+2), 2-iter lead

    if (t < 31) {
      asm volatile("s_waitcnt vmcnt(5)" ::: "memory");  // tile-t retired; t+1's 4 + S in flight
    } else {
      asm volatile("s_waitcnt vmcnt(0)" ::: "memory");  // final tile
    }
    asm volatile("s_waitcnt lgkmcnt(0)" ::: "memory");  // my A ds_writes done
    __builtin_amdgcn_s_barrier();
    __builtin_amdgcn_sched_barrier(0);

#pragma unroll
    for (int kk = 0; kk < 2; ++kk) {
      const int slot = (wk * 2 + kk) * 2 + lh;     // 0..7
      const int ra0 = l31, ra1 = 32 + l31;
      const int rb0 = wd * 64 + l31, rb1 = wd * 64 + 32 + l31;
      bf16x8 a0 = *(const bf16x8*)&At[cur][ra0 * 64 + ((slot ^ (ra0 & 7)) << 3)];
      bf16x8 a1f = *(const bf16x8*)&At[cur][ra1 * 64 + ((slot ^ (ra1 & 7)) << 3)];
      bf16x8 b0 = *(const bf16x8*)&Bt[cur][rb0 * 64 + ((slot ^ (rb0 & 7)) << 3)];
      bf16x8 b1 = *(const bf16x8*)&Bt[cur][rb1 * 64 + ((slot ^ (rb1 & 7)) << 3)];
      acc[0][0] = __builtin_amdgcn_mfma_f32_32x32x16_bf16(a0, b0, acc[0][0], 0, 0, 0);
      acc[0][1] = __builtin_amdgcn_mfma_f32_32x32x16_bf16(a0, b1, acc[0][1], 0, 0, 0);
      acc[1][0] = __builtin_amdgcn_mfma_f32_32x32x16_bf16(a1f, b0, acc[1][0], 0, 0, 0);
      acc[1][1] = __builtin_amdgcn_mfma_f32_32x32x16_bf16(a1f, b1, acc[1][1], 0, 0, 0);
    }

    __builtin_amdgcn_sched_barrier(0);
    __builtin_amdgcn_s_barrier();   // all reads of cur done before next writes
  }

  // den partials + k-half merge (all MFMA reads done at the final barrier)
  denp[tid] = loc;
  int qrow[16];
#pragma unroll
  for (int r = 0; r < 16; ++r) qrow[r] = (r & 3) + 8 * (r >> 2) + 4 * lh;

  float* Lred = (float*)&Bt[0][0];   // 64x256 f32 = 64 KB, exactly Bt
  if (wk == 1) {
#pragma unroll
    for (int i = 0; i < 2; ++i)
#pragma unroll
      for (int j = 0; j < 2; ++j)
#pragma unroll
        for (int r = 0; r < 16; ++r) {
          int row = i * 32 + qrow[r];
          Lred[row * 256 + wd * 64 + j * 32 + l31] = acc[i][j][r];
        }
  }
  __syncthreads();
  if (tid < 64) {
    float s = 0.f;
#pragma unroll
    for (int c = 0; c < 8; ++c) s += denp[tid * 8 + c];
    dinv[tid] = 1.0f / s;
  }
  __syncthreads();
  if (wk == 0) {
    float* Ob = out + ((size_t)b * SS + q0) * DD + d0 + wd * 64;
#pragma unroll
    for (int i = 0; i < 2; ++i)
#pragma unroll
      for (int j = 0; j < 2; ++j)
#pragma unroll
        for (int r = 0; r < 16; ++r) {
          int row = i * 32 + qrow[r];
          Ob[(size_t)row * DD + j * 32 + l31] =
              (acc[i][j][r] + Lred[row * 256 + wd * 64 + j * 32 + l31]) * dinv[row];
        }
  }
#undef EXPWRITE
#undef STAGEB
}

// ---------------- fallback (round-1 kernel, zero workspace) ----------------

#define QS_STRIDE 520
#define KS_STRIDE 72
#define VT_STRIDE 18
#define PS_STRIDE 136

__device__ __forceinline__ f32x16 qk_tile(const float* __restrict__ Kb,
                                          const bf16* __restrict__ Qsl,
                                          bf16* __restrict__ KVw,
                                          int l31, int lh8, int lane) {
  f32x16 acc = {};
  for (int dc = 0; dc < DD; dc += 64) {
#pragma unroll
    for (int i = 0; i < 8; ++i) {
      int f = i * 64 + lane;
      int row = f >> 4;
      int c4 = (f & 15) * 4;
      float4 v = *(const float4*)(Kb + row * DD + dc + c4);
      bf16x4 h = { (bf16)v.x, (bf16)v.y, (bf16)v.z, (bf16)v.w };
      *(bf16x4*)&KVw[row * KS_STRIDE + c4] = h;
    }
#pragma unroll
    for (int ks = 0; ks < 4; ++ks) {
      bf16x8 a  = *(const bf16x8*)&Qsl[l31 * QS_STRIDE + dc + ks * 16 + lh8];
      bf16x8 bb = *(const bf16x8*)&KVw[l31 * KS_STRIDE + ks * 16 + lh8];
      acc = __builtin_amdgcn_mfma_f32_32x32x16_bf16(a, bb, acc, 0, 0, 0);
    }
  }
  return acc;
}

__launch_bounds__(256, 1)
__global__ void nm_attn_kernel(const float* __restrict__ Qp,
                               const float* __restrict__ Kp,
                               const float* __restrict__ Vp,
                               float* __restrict__ Op) {
  __shared__ bf16 Qs[32 * QS_STRIDE];
  __shared__ bf16 KVu[4][32 * KS_STRIDE];
  __shared__ bf16 Psl[32 * PS_STRIDE];
  __shared__ float redA[4][32];
  __shared__ float redB[4][32];
  __shared__ float a0v[32], a1v[32], idv[32];

  const int tid  = threadIdx.x;
  const int w    = tid >> 6;
  const int lane = tid & 63;
  const int l31  = lane & 31;
  const int lh8  = (lane >> 5) * 8;
  const int b    = blockIdx.y;
  const int q0   = blockIdx.x * 32;

  {
    const float* Qbase = Qp + (size_t)(b * SS + q0) * DD;
#pragma unroll
    for (int i = 0; i < 16; ++i) {
      int f = i * 256 + tid;
      int row = f >> 7;
      int c4 = (f & 127) * 4;
      float4 v = *(const float4*)(Qbase + row * DD + c4);
      bf16x4 h = { (bf16)v.x, (bf16)v.y, (bf16)v.z, (bf16)v.w };
      *(bf16x4*)&Qs[row * QS_STRIDE + c4] = h;
    }
  }
  __syncthreads();

  int qrow[16];
#pragma unroll
  for (int r = 0; r < 16; ++r) qrow[r] = (r & 3) + 8 * (r >> 2) + 4 * (lane >> 5);

  float sumv[16], sqv[16];
#pragma unroll
  for (int r = 0; r < 16; ++r) { sumv[r] = 0.f; sqv[r] = 0.f; }

  for (int kt = 0; kt < 16; ++kt) {
    const float* Kb = Kp + (size_t)(b * SS + kt * 128 + w * 32) * DD;
    f32x16 acc = qk_tile(Kb, Qs, KVu[w], l31, lh8, lane);
#pragma unroll
    for (int r = 0; r < 16; ++r) {
      float s = acc[r] * SCALE;
      sumv[r] += s;
      sqv[r]  += s * s;
    }
  }

#pragma unroll
  for (int r = 0; r < 16; ++r) {
    float v1 = sumv[r], v2 = sqv[r];
#pragma unroll
    for (int m = 16; m >= 1; m >>= 1) {
      v1 += __shfl_xor(v1, m);
      v2 += __shfl_xor(v2, m);
    }
    if (l31 == 0) { redA[w][qrow[r]] = v1; redB[w][qrow[r]] = v2; }
  }
  __syncthreads();
  if (tid < 32) {
    float s  = redA[0][tid] + redA[1][tid] + redA[2][tid] + redA[3][tid];
    float sq = redB[0][tid] + redB[1][tid] + redB[2][tid] + redB[3][tid];
    float mean = s * (1.0f / 2048.0f);
    float var = (sq - 2048.0f * mean * mean) * (1.0f / 2047.0f);
    var = fmaxf(var, 0.0f);
    float istd = 1.0f / (sqrtf(var) + 1e-6f);
    a1v[tid] = istd * LOG2E;
    a0v[tid] = -mean * istd * LOG2E;
  }
  __syncthreads();

  float a0r[16], a1r[16], den[16];
#pragma unroll
  for (int r = 0; r < 16; ++r) {
    a0r[r] = a0v[qrow[r]];
    a1r[r] = a1v[qrow[r]];
    den[r] = 0.f;
  }

  f32x16 Oa[4] = {};

  for (int kt = 0; kt < 16; ++kt) {
    const float* Kb = Kp + (size_t)(b * SS + kt * 128 + w * 32) * DD;
    f32x16 acc = qk_tile(Kb, Qs, KVu[w], l31, lh8, lane);

    __syncthreads();
#pragma unroll
    for (int r = 0; r < 16; ++r) {
      float s = acc[r] * SCALE;
      float p = exp2f(fmaf(s, a1r[r], a0r[r]));
      den[r] += p;
      Psl[qrow[r] * PS_STRIDE + w * 32 + l31] = (bf16)p;
    }
    __syncthreads();

    const float* Vb = Vp + (size_t)(b * SS + kt * 128) * DD + w * 128 + 2 * lane;
    bf16* Vts = KVu[w];
    const int d0 = 2 * lane;
    for (int ks2 = 0; ks2 < 8; ++ks2) {
      const float* Vk = Vb + ks2 * 16 * DD;
#pragma unroll
      for (int i = 0; i < 8; ++i) {
        float2 va = *(const float2*)(Vk + (2 * i) * DD);
        float2 vc = *(const float2*)(Vk + (2 * i + 1) * DD);
        bf16x2 h0 = { (bf16)va.x, (bf16)vc.x };
        bf16x2 h1 = { (bf16)va.y, (bf16)vc.y };
        *(bf16x2*)&Vts[d0 * VT_STRIDE + 2 * i] = h0;
        *(bf16x2*)&Vts[(d0 + 1) * VT_STRIDE + 2 * i] = h1;
      }
      bf16x8 aP = *(const bf16x8*)&Psl[l31 * PS_STRIDE + ks2 * 16 + lh8];
#pragma unroll
      for (int dt = 0; dt < 4; ++dt) {
        const bf16* vr = &Vts[(dt * 32 + l31) * VT_STRIDE + lh8];
        bf16x2 e0 = *(const bf16x2*)(vr + 0);
        bf16x2 e1 = *(const bf16x2*)(vr + 2);
        bf16x2 e2 = *(const bf16x2*)(vr + 4);
        bf16x2 e3 = *(const bf16x2*)(vr + 6);
        bf16x8 bV = { e0.x, e0.y, e1.x, e1.y, e2.x, e2.y, e3.x, e3.y };
        Oa[dt] = __builtin_amdgcn_mfma_f32_32x32x16_bf16(aP, bV, Oa[dt], 0, 0, 0);
      }
    }
  }

#pragma unroll
  for (int r = 0; r < 16; ++r) {
    float v1 = den[r];
#pragma unroll
    for (int m = 16; m >= 1; m >>= 1) v1 += __shfl_xor(v1, m);
    if (l31 == 0) redA[w][qrow[r]] = v1;
  }
  __syncthreads();
  if (tid < 32) {
    float t = redA[0][tid] + redA[1][tid] + redA[2][tid] + redA[3][tid];
    idv[tid] = 1.0f / t;
  }
  __syncthreads();

  float idr[16];
#pragma unroll
  for (int r = 0; r < 16; ++r) idr[r] = idv[qrow[r]];

  float* Ob = Op + (size_t)(b * SS + q0) * DD + w * 128;
#pragma unroll
  for (int dt = 0; dt < 4; ++dt) {
#pragma unroll
    for (int r = 0; r < 16; ++r) {
      Ob[qrow[r] * DD + dt * 32 + l31] = Oa[dt][r] * idr[r];
    }
  }
}

// ---------------- launcher ----------------

extern "C" void kernel_launch(void* const* d_in, const int* in_sizes, int n_in,
                              void* d_out, int out_size, void* d_ws, size_t ws_size,
                              hipStream_t stream) {
  const float* Q = (const float*)d_in[0];
  const float* K = (const float*)d_in[1];
  const float* V = (const float*)d_in[2];
  float* out = (float*)d_out;
  (void)in_sizes; (void)n_in; (void)out_size;

  const size_t E  = (size_t)BB * SS * DD;   // 4,194,304 elems / tensor
  const size_t SE = (size_t)BB * SS * SS;   // 16,777,216 score elems

  // ws layout: [Qb bf16 E][Kb bf16 E][Vt bf16 E][S f16 SE][a1 B*S f32]
  const size_t off_Kb  = E * sizeof(bf16);
  const size_t off_Vt  = off_Kb + E * sizeof(bf16);
  const size_t off_S   = off_Vt + E * sizeof(bf16);
  const size_t off_a1  = off_S + SE * sizeof(f16);
  const size_t need    = off_a1 + (size_t)BB * SS * sizeof(float);  // ~58.8 MB

  if (ws_size >= need) {
    char* ws = (char*)d_ws;
    bf16*  Qb  = (bf16*)ws;
    bf16*  Kb  = (bf16*)(ws + off_Kb);
    bf16*  Vt  = (bf16*)(ws + off_Vt);
    f16*   Sp  = (f16*)(ws + off_S);
    float* a1p = (float*)(ws + off_a1);

    prep_kernel<<<2048 + 1024, 256, 0, stream>>>(Q, K, V, Qb, Kb, Vt);
    qk_gemm_kernel<<<dim3(SS / 128, SS / 256, BB), 256, 0, stream>>>(Qb, Kb, Sp);
    stats_kernel<<<dim3(SS, BB), 256, 0, stream>>>(Sp, a1p);
    smpv_kernel<<<256, 512, 0, stream>>>(Sp, Vt, a1p, out);
  } else {
    nm_attn_kernel<<<dim3(SS / 32, BB), dim3(256, 1, 1), 0, stream>>>(Q, K, V, out);
  }
}